// Round 15
// baseline (398.247 us; speedup 1.0000x reference)
//
#include <hip/hip_runtime.h>
#include <hip/hip_cooperative_groups.h>
#include <math.h>

#define S_ 2048
#define NH 8
#define RSTRIDE 264
#define LP 72
#define ARENA_SHORTS 13824   // 27648 B: fits phase C (128x72 + 64x72)

namespace cg = cooperative_groups;

typedef __attribute__((ext_vector_type(8))) short short8;   // 8 x bf16
typedef __attribute__((ext_vector_type(4))) float f32x4;    // MFMA accumulator
typedef unsigned short ushort_t;

__device__ __forceinline__ short bf16r(float x) {   // RNE float->bf16
    union { float f; unsigned u; } v; v.f = x;
    unsigned r = v.u + 0x7fffu + ((v.u >> 16) & 1u);
    return (short)(r >> 16);
}
__device__ __forceinline__ float b2f(ushort_t h) {  // bf16->float
    union { float f; unsigned u; } v; v.u = ((unsigned)h) << 16; return v.f;
}

// ===========================================================================
// Phase bodies (shared between the cooperative kernel and the fallback
// standalone kernels — identical math on both paths).
// ===========================================================================

// ---- Phase A: weight transposes (256 tasks) + pos table (64 tasks) --------
__device__ __forceinline__ void phaseA(
    int bid, int tid, ushort_t* arena,
    const float* __restrict__ Wq, const float* __restrict__ Wk,
    const float* __restrict__ Wv, const float* __restrict__ Wkr,
    ushort_t* __restrict__ WTq, ushort_t* __restrict__ WTk,
    ushort_t* __restrict__ WTv, ushort_t* __restrict__ WTkr,
    ushort_t* __restrict__ pos)
{
    if (bid < 256) {
        const int widx = bid >> 6;
        const float* W = (widx == 0) ? Wq : (widx == 1) ? Wk : (widx == 2) ? Wv : Wkr;
        ushort_t* WT   = (widx == 0) ? WTq : (widx == 1) ? WTk : (widx == 2) ? WTv : WTkr;
        const int sub = bid & 63;
        const int k0 = (sub >> 3) * 64, n0 = (sub & 7) * 64;
        ushort_t (*T)[72] = (ushort_t(*)[72])arena;
        const int srow = tid >> 2, sc0 = (tid & 3) * 16;
        const float* src = &W[(size_t)(k0 + srow) * 512 + n0 + sc0];
#pragma unroll
        for (int u = 0; u < 16; ++u) T[sc0 + u][srow] = (ushort_t)bf16r(src[u]);
        __syncthreads();
        ushort_t* dst = &WT[(size_t)(n0 + srow) * 512 + k0 + sc0];
        *(short8*)dst       = *(const short8*)&T[srow][sc0];
        *(short8*)(dst + 8) = *(const short8*)&T[srow][sc0 + 8];
    } else if (bid < 320) {
        const int base = bid - 256;                      // 0..63
        const float C = -0.051905126482615036f;          // -log2(10000)/256
        const int f = tid;
#pragma unroll
        for (int rep = 0; rep < 6; ++rep) {
            const int r = base + rep * 64;               // 0..383
            unsigned pk = 0;
            if (r <= 256) {
                float ang = (float)r * exp2f(C * (float)f);
                unsigned s = (unsigned)(ushort_t)bf16r(sinf(ang));
                unsigned c = (unsigned)(ushort_t)bf16r(cosf(ang));
                pk = s | (c << 16);
            }
            ((unsigned*)pos)[(size_t)r * 256 + f] = pk;
        }
    }
}

// ---- Phase B: qkv / vT / krel as 1584 64x64 MFMA tasks --------------------
__device__ __forceinline__ void phaseB(
    int bid, int tid, ushort_t* arena,
    const float* __restrict__ x,
    const ushort_t* __restrict__ WTq, const ushort_t* __restrict__ WTk,
    const ushort_t* __restrict__ WTv,
    const ushort_t* __restrict__ pos, const ushort_t* __restrict__ WTkr,
    const float* __restrict__ b_con, const float* __restrict__ b_rel,
    const float* __restrict__ bv,
    ushort_t* __restrict__ qcon, ushort_t* __restrict__ qrel,
    ushort_t* __restrict__ kbuf, ushort_t* __restrict__ vT,
    ushort_t* __restrict__ krel)
{
    const int lane = tid & 63, w4 = tid >> 6;
    const int quad = lane >> 4, l16 = lane & 15;
    ushort_t (*A_lds)[40] = (ushort_t(*)[40])arena;            // 64x40
    ushort_t (*B_lds)[40] = (ushort_t(*)[40])(arena + 2560);   // 64x40
    const int arow = tid >> 2, ak0 = (tid & 3) * 8;

    for (int task = bid; task < 1584; task += 512) {
        f32x4 acc[4];
#pragma unroll
        for (int nt = 0; nt < 4; ++nt) acc[nt] = (f32x4){0.f, 0.f, 0.f, 0.f};

        if (task < 1024) {
            // ---- qcon/qrel (widx 0) or k (widx 1): out = x @ W ----
            const int widx = task >> 9;
            const int rem = task & 511;
            const int m0 = (rem >> 3) * 64, n0 = (rem & 7) * 64;
            const ushort_t* WT = (widx == 0) ? WTq : WTk;
            const float* xrow = &x[(size_t)(m0 + arow) * 512 + ak0];
            const ushort_t* wrow = &WT[(size_t)(n0 + arow) * 512 + ak0];
            float4 pa0 = *(const float4*)xrow;
            float4 pa1 = *(const float4*)(xrow + 4);
            short8 pb = *(const short8*)wrow;
#pragma unroll 1
            for (int k0 = 0; k0 < 512; k0 += 32) {
                __syncthreads();
                {
                    float pf[8];
                    *(float4*)&pf[0] = pa0; *(float4*)&pf[4] = pa1;
                    ushort_t t8[8];
#pragma unroll
                    for (int u = 0; u < 8; ++u) t8[u] = (ushort_t)bf16r(pf[u]);
                    *(short8*)&A_lds[arow][ak0] = *(short8*)&t8[0];
                    *(short8*)&B_lds[arow][ak0] = pb;
                }
                if (k0 < 480) {
                    pa0 = *(const float4*)(xrow + k0 + 32);
                    pa1 = *(const float4*)(xrow + k0 + 36);
                    pb  = *(const short8*)(wrow + k0 + 32);
                }
                __syncthreads();
                short8 a0 = *(const short8*)&A_lds[w4 * 16 + l16][quad * 8];
#pragma unroll
                for (int nt = 0; nt < 4; ++nt) {
                    short8 bb = *(const short8*)&B_lds[nt * 16 + l16][quad * 8];
                    acc[nt] = __builtin_amdgcn_mfma_f32_16x16x32_bf16(a0, bb, acc[nt], 0, 0, 0);
                }
            }
#pragma unroll
            for (int nt = 0; nt < 4; ++nt) {
                const int col = n0 + nt * 16 + l16;
                float bc = 0.f, br = 0.f;
                if (widx == 0) { bc = b_con[col]; br = b_rel[col]; }
#pragma unroll
                for (int reg = 0; reg < 4; ++reg) {
                    const size_t m = (size_t)(m0 + w4 * 16 + quad * 4 + reg);
                    const float val = acc[nt][reg];
                    if (widx == 0) {
                        qcon[m * 512 + col] = (ushort_t)bf16r((val + bc) * 0.125f);
                        qrel[m * 512 + col] = (ushort_t)bf16r((val + br) * 0.125f);
                    } else {
                        kbuf[m * 512 + col] = (ushort_t)bf16r(val);
                    }
                }
            }
        } else if (task < 1536) {
            // ---- V transposed: vT[d][j] = WTv[d] . x[j] + bv[d] ----
            const int vt = task - 1024;
            const int m0d = (vt & 7) * 64;
            const int n0j = (vt >> 3) * 64;
            const ushort_t* wrow = &WTv[(size_t)(m0d + arow) * 512 + ak0];
            const float* xrow = &x[(size_t)(n0j + arow) * 512 + ak0];
            short8 pa = *(const short8*)wrow;
            float4 pb0 = *(const float4*)xrow;
            float4 pb1 = *(const float4*)(xrow + 4);
#pragma unroll 1
            for (int k0 = 0; k0 < 512; k0 += 32) {
                __syncthreads();
                {
                    *(short8*)&A_lds[arow][ak0] = pa;
                    float pf[8];
                    *(float4*)&pf[0] = pb0; *(float4*)&pf[4] = pb1;
                    ushort_t t8[8];
#pragma unroll
                    for (int u = 0; u < 8; ++u) t8[u] = (ushort_t)bf16r(pf[u]);
                    *(short8*)&B_lds[arow][ak0] = *(short8*)&t8[0];
                }
                if (k0 < 480) {
                    pa  = *(const short8*)(wrow + k0 + 32);
                    pb0 = *(const float4*)(xrow + k0 + 32);
                    pb1 = *(const float4*)(xrow + k0 + 36);
                }
                __syncthreads();
                short8 a0 = *(const short8*)&A_lds[w4 * 16 + l16][quad * 8];
#pragma unroll
                for (int nt = 0; nt < 4; ++nt) {
                    short8 bb = *(const short8*)&B_lds[nt * 16 + l16][quad * 8];
                    acc[nt] = __builtin_amdgcn_mfma_f32_16x16x32_bf16(a0, bb, acc[nt], 0, 0, 0);
                }
            }
            float bvv[4];
#pragma unroll
            for (int reg = 0; reg < 4; ++reg)
                bvv[reg] = bv[m0d + w4 * 16 + quad * 4 + reg];
#pragma unroll
            for (int nt = 0; nt < 4; ++nt) {
                const int sg = n0j + nt * 16 + l16;
                const int b = sg >> 11, s = sg & 2047;
#pragma unroll
                for (int reg = 0; reg < 4; ++reg) {
                    const int d = m0d + w4 * 16 + quad * 4 + reg;
                    const int n = d >> 6, dd = d & 63;
                    vT[((size_t)((b * NH + n) * 64 + dd)) * 2048 + s] =
                        (ushort_t)bf16r(acc[nt][reg] + bvv[reg]);
                }
            }
        } else {
            // ---- krel = pos @ Wkr ----
            const int kt = task - 1536;
            const int m0 = (kt >> 3) * 64, n0 = (kt & 7) * 64;
            const ushort_t* prow = &pos[(size_t)(m0 + arow) * 512 + ak0];
            const ushort_t* wrow = &WTkr[(size_t)(n0 + arow) * 512 + ak0];
            short8 pa = *(const short8*)prow;
            short8 pb = *(const short8*)wrow;
#pragma unroll 1
            for (int k0 = 0; k0 < 512; k0 += 32) {
                __syncthreads();
                *(short8*)&A_lds[arow][ak0] = pa;
                *(short8*)&B_lds[arow][ak0] = pb;
                if (k0 < 480) {
                    pa = *(const short8*)(prow + k0 + 32);
                    pb = *(const short8*)(wrow + k0 + 32);
                }
                __syncthreads();
                short8 a0 = *(const short8*)&A_lds[w4 * 16 + l16][quad * 8];
#pragma unroll
                for (int nt = 0; nt < 4; ++nt) {
                    short8 bb = *(const short8*)&B_lds[nt * 16 + l16][quad * 8];
                    acc[nt] = __builtin_amdgcn_mfma_f32_16x16x32_bf16(a0, bb, acc[nt], 0, 0, 0);
                }
            }
#pragma unroll
            for (int nt = 0; nt < 4; ++nt) {
                const int col = n0 + nt * 16 + l16;
#pragma unroll
                for (int reg = 0; reg < 4; ++reg) {
                    const size_t m = (size_t)(m0 + w4 * 16 + quad * 4 + reg);
                    krel[m * 512 + col] = (ushort_t)bf16r(acc[nt][reg]);
                }
            }
        }
    }
}

// ---- Phase C: rel GEMM (256 tasks) + vmean (16 tasks) ---------------------
__device__ __forceinline__ void phaseC(
    int bid, int tid, ushort_t* arena,
    const ushort_t* __restrict__ qrel, const ushort_t* __restrict__ krel,
    const ushort_t* __restrict__ vT, ushort_t* __restrict__ R,
    float* __restrict__ vmean)
{
    const int lane = tid & 63, w4 = tid >> 6;
    const int quad = lane >> 4, l16 = lane & 15;

    if (bid >= 272) return;
    if (bid >= 256) {
        const int vt = bid - 256;
        const int b = vt >> 3, n = vt & 7;
        const int row = tid >> 2, seg = tid & 3;
        const ushort_t* src =
            &vT[((size_t)((b * NH + n) * 64 + row)) * 2048 + seg * 512];
        float sum = 0.f;
        for (int it = 0; it < 64; ++it) {
            short8 h = *(const short8*)(src + it * 8);
#pragma unroll
            for (int u = 0; u < 8; ++u) sum += b2f((ushort_t)h[u]);
        }
        float* scratch = (float*)arena;
        scratch[row * 4 + seg] = sum;
        __syncthreads();
        if (tid < 64) {
            float s = scratch[tid * 4] + scratch[tid * 4 + 1]
                    + scratch[tid * 4 + 2] + scratch[tid * 4 + 3];
            vmean[(size_t)b * 512 + n * 64 + tid] = s * (1.0f / (float)S_);
        }
        return;
    }

    const int tile = bid & 15, n = (bid >> 4) & 7, b = bid >> 7;
    const int i0 = tile * 128;
    ushort_t (*A2)[LP] = (ushort_t(*)[LP])arena;            // 128x72
    ushort_t (*B2)[LP] = (ushort_t(*)[LP])(arena + 9216);   // 64x72
    {
        const int srow = tid >> 1, sc0b = (tid & 1) * 32;
        const ushort_t* src = &qrel[((size_t)b * S_ + i0 + srow) * 512 + n * 64 + sc0b];
#pragma unroll
        for (int u = 0; u < 4; ++u)
            *(short8*)&A2[srow][sc0b + u * 8] = *(const short8*)(src + u * 8);
    }
    const size_t rbase = ((size_t)(b * NH + n) * S_ + i0) * RSTRIDE;
    const int srow2 = tid >> 2, sc2 = (tid & 3) * 16;
    const ushort_t* kr0 = &krel[(size_t)srow2 * 512 + n * 64 + sc2];
    short8 pb0 = *(const short8*)kr0;
    short8 pb1 = *(const short8*)(kr0 + 8);
#pragma unroll 1
    for (int rc = 0; rc < 5; ++rc) {
        __syncthreads();
        *(short8*)&B2[srow2][sc2]     = pb0;
        *(short8*)&B2[srow2][sc2 + 8] = pb1;
        if (rc < 4) {
            const ushort_t* src =
                &krel[(size_t)((rc + 1) * 64 + srow2) * 512 + n * 64 + sc2];
            pb0 = *(const short8*)src;
            pb1 = *(const short8*)(src + 8);
        }
        __syncthreads();
        short8 a[2][2];
#pragma unroll
        for (int mt = 0; mt < 2; ++mt) {
            a[mt][0] = *(const short8*)&A2[w4 * 32 + mt * 16 + l16][quad * 8];
            a[mt][1] = *(const short8*)&A2[w4 * 32 + mt * 16 + l16][quad * 8 + 32];
        }
#pragma unroll
        for (int nt = 0; nt < 4; ++nt) {
            short8 b0 = *(const short8*)&B2[nt * 16 + l16][quad * 8];
            short8 b1 = *(const short8*)&B2[nt * 16 + l16][quad * 8 + 32];
            const int r = rc * 64 + nt * 16 + l16;
#pragma unroll
            for (int mt = 0; mt < 2; ++mt) {
                f32x4 s = (f32x4){0.f, 0.f, 0.f, 0.f};
                s = __builtin_amdgcn_mfma_f32_16x16x32_bf16(a[mt][0], b0, s, 0, 0, 0);
                s = __builtin_amdgcn_mfma_f32_16x16x32_bf16(a[mt][1], b1, s, 0, 0, 0);
                if (r < RSTRIDE) {
#pragma unroll
                    for (int reg = 0; reg < 4; ++reg) {
                        const int i = w4 * 32 + mt * 16 + quad * 4 + reg;
                        R[rbase + (size_t)i * RSTRIDE + r] = (ushort_t)bf16r(s[reg]);
                    }
                }
            }
        }
    }
}

// ===========================================================================
// Cooperative front kernel: A -> grid.sync -> B -> grid.sync -> C.
// Arena 27.6 KB: >=2 blocks/CU under BOTH plausible runtime occupancy models
// (64 KB or 160 KB LDS/CU) -> coop grid 512 passes the residency check
// (round-14's 55.3 KB arena was the likely cooperativeLaunchTooLarge cause).
// ===========================================================================
__global__ __launch_bounds__(256, 2) void fused_front(
    const float* __restrict__ x,
    const float* __restrict__ Wq, const float* __restrict__ Wk,
    const float* __restrict__ Wv, const float* __restrict__ Wkr,
    const float* __restrict__ b_con, const float* __restrict__ b_rel,
    const float* __restrict__ bv,
    ushort_t* __restrict__ WTq, ushort_t* __restrict__ WTk,
    ushort_t* __restrict__ WTv, ushort_t* __restrict__ WTkr,
    ushort_t* __restrict__ pos,
    ushort_t* __restrict__ qcon, ushort_t* __restrict__ qrel,
    ushort_t* __restrict__ kbuf, ushort_t* __restrict__ vT,
    ushort_t* __restrict__ krel, ushort_t* __restrict__ R,
    float* __restrict__ vmean)
{
    cg::grid_group grid = cg::this_grid();
    __shared__ __align__(16) ushort_t arena[ARENA_SHORTS];
    phaseA(blockIdx.x, threadIdx.x, arena, Wq, Wk, Wv, Wkr,
           WTq, WTk, WTv, WTkr, pos);
    __threadfence();
    grid.sync();
    phaseB(blockIdx.x, threadIdx.x, arena, x, WTq, WTk, WTv, pos, WTkr,
           b_con, b_rel, bv, qcon, qrel, kbuf, vT, krel);
    __threadfence();
    grid.sync();
    phaseC(blockIdx.x, threadIdx.x, arena, qrel, krel, vT, R, vmean);
}

// ---- Fallback standalone kernels (identical phase bodies) -----------------
__global__ __launch_bounds__(256) void kA(
    const float* Wq, const float* Wk, const float* Wv, const float* Wkr,
    ushort_t* WTq, ushort_t* WTk, ushort_t* WTv, ushort_t* WTkr, ushort_t* pos)
{
    __shared__ __align__(16) ushort_t arena[ARENA_SHORTS];
    phaseA(blockIdx.x, threadIdx.x, arena, Wq, Wk, Wv, Wkr, WTq, WTk, WTv, WTkr, pos);
}
__global__ __launch_bounds__(256) void kB(
    const float* x, const ushort_t* WTq, const ushort_t* WTk, const ushort_t* WTv,
    const ushort_t* pos, const ushort_t* WTkr,
    const float* b_con, const float* b_rel, const float* bv,
    ushort_t* qcon, ushort_t* qrel, ushort_t* kbuf, ushort_t* vT, ushort_t* krel)
{
    __shared__ __align__(16) ushort_t arena[ARENA_SHORTS];
    phaseB(blockIdx.x, threadIdx.x, arena, x, WTq, WTk, WTv, pos, WTkr,
           b_con, b_rel, bv, qcon, qrel, kbuf, vT, krel);
}
__global__ __launch_bounds__(256) void kC(
    const ushort_t* qrel, const ushort_t* krel, const ushort_t* vT,
    ushort_t* R, float* vmean)
{
    __shared__ __align__(16) ushort_t arena[ARENA_SHORTS];
    phaseC(blockIdx.x, threadIdx.x, arena, qrel, krel, vT, R, vmean);
}

// ===========================================================================
// Attention: R13's tuned kernel verbatim (1024 x 128, 27.6 KB LDS, register
// prefetch of next chunk's k/vT/R, XCD swizzle).
// ===========================================================================
__global__ __launch_bounds__(128) void attn_kernel(
    const ushort_t* __restrict__ qcon, const ushort_t* __restrict__ kbuf,
    const ushort_t* __restrict__ vT, const ushort_t* __restrict__ R,
    const float* __restrict__ vmean, const int* __restrict__ xlen_p,
    float* __restrict__ out)
{
    const int bx = blockIdx.x;
    const int tile = ((bx & 7) << 3) | (bx >> 3);   // XCD swizzle
    const int n = blockIdx.y, b = blockIdx.z;
    const int i0 = tile * 32;
    const int tid = threadIdx.x, lane = tid & 63, w = tid >> 6;
    const int quad = lane >> 4, l16 = lane & 15;
    const int xlen = xlen_p[b];

    __shared__ __align__(16) ushort_t q_lds[32][LP];
    __shared__ __align__(16) ushort_t k_lds[64][LP];
    __shared__ __align__(16) ushort_t vT_lds[64][LP];
    __shared__ __align__(16) ushort_t p_lds[32][LP];

    {
        const int qr = tid >> 2, qc = (tid & 3) * 16;
        const ushort_t* src = &qcon[((size_t)b * S_ + i0 + qr) * 512 + n * 64 + qc];
        *(short8*)&q_lds[qr][qc]     = *(const short8*)src;
        *(short8*)&q_lds[qr][qc + 8] = *(const short8*)(src + 8);
    }

    f32x4 Oa[4];
#pragma unroll
    for (int nt = 0; nt < 4; ++nt) Oa[nt] = (f32x4){0.f, 0.f, 0.f, 0.f};
    float lpart[4] = {};

    const size_t rrowB = (size_t)(b * NH + n) * S_ * RSTRIDE;
    const size_t vTbase = (size_t)((b * NH + n) * 64) * 2048;
    const int srow = tid >> 1, sc0 = (tid & 1) * 32;
    const short8 z8 = {0, 0, 0, 0, 0, 0, 0, 0};

    short8 kr[4], vr[4], kn[4], vn[4];
    ushort_t rc_[16], rn_[16];

    auto issue = [&](int c, short8* kd, short8* vd, ushort_t* rd) {
        const int jc0 = i0 - 256 + c * 64;
        const int jg = jc0 + srow;
        const bool okk = (jg >= 0);
        const ushort_t* ks = &kbuf[((size_t)b * S_ + jg) * 512 + n * 64 + sc0];
        const ushort_t* vs = &vT[vTbase + (size_t)srow * 2048 + jc0 + sc0];
#pragma unroll
        for (int u = 0; u < 4; ++u) {
            kd[u] = okk ? *(const short8*)(ks + u * 8) : z8;
            const bool okv = (jc0 + sc0 + u * 8) >= 0;
            vd[u] = okv ? *(const short8*)(vs + u * 8) : z8;
        }
#pragma unroll
        for (int jt = 0; jt < 4; ++jt) {
#pragma unroll
            for (int reg = 0; reg < 4; ++reg) {
                const int i = i0 + w * 16 + quad * 4 + reg;
                const int j = jc0 + jt * 16 + l16;
                const int r = i - j;
                const bool valid = (j >= 0) && (j < xlen) && (r >= 0) && (r <= 256);
                rd[jt * 4 + reg] = valid ? R[rrowB + (size_t)i * RSTRIDE + r]
                                         : (ushort_t)0;
            }
        }
    };

    issue(0, kr, vr, rc_);

#pragma unroll 1
    for (int c = 0; c < 5; ++c) {
        const int jc0 = i0 - 256 + c * 64;
        __syncthreads();   // prev-chunk PV reads of k/vT/p done
#pragma unroll
        for (int u = 0; u < 4; ++u) {
            *(short8*)&k_lds[srow][sc0 + u * 8]  = kr[u];
            *(short8*)&vT_lds[srow][sc0 + u * 8] = vr[u];
        }
        if (c < 4) issue(c + 1, kn, vn, rn_);
        __syncthreads();

        // ---- QK ----
        short8 aq0 = *(const short8*)&q_lds[w * 16 + l16][quad * 8];
        short8 aq1 = *(const short8*)&q_lds[w * 16 + l16][quad * 8 + 32];
        f32x4 Sacc[4];
#pragma unroll
        for (int jt = 0; jt < 4; ++jt) {
            short8 bk0 = *(const short8*)&k_lds[jt * 16 + l16][quad * 8];
            short8 bk1 = *(const short8*)&k_lds[jt * 16 + l16][quad * 8 + 32];
            f32x4 s = (f32x4){0.f, 0.f, 0.f, 0.f};
            s = __builtin_amdgcn_mfma_f32_16x16x32_bf16(aq0, bk0, s, 0, 0, 0);
            s = __builtin_amdgcn_mfma_f32_16x16x32_bf16(aq1, bk1, s, 0, 0, 0);
            Sacc[jt] = s;
        }

        // ---- mask + rel bias + exp; p -> LDS bf16 ----
#pragma unroll
        for (int jt = 0; jt < 4; ++jt) {
#pragma unroll
            for (int reg = 0; reg < 4; ++reg) {
                const int i = i0 + w * 16 + quad * 4 + reg;
                const int j = jc0 + jt * 16 + l16;
                const int r = i - j;
                const bool valid = (j >= 0) && (j < xlen) && (r >= 0) && (r <= 256);
                float e = valid ? __expf(Sacc[jt][reg] + b2f(rc_[jt * 4 + reg])) : 0.f;
                lpart[reg] += e;
                p_lds[w * 16 + quad * 4 + reg][jt * 16 + l16] = (ushort_t)bf16r(e);
            }
        }
        __syncthreads();

        // ---- PV ----
        short8 ap0 = *(const short8*)&p_lds[w * 16 + l16][quad * 8];
        short8 ap1 = *(const short8*)&p_lds[w * 16 + l16][quad * 8 + 32];
#pragma unroll
        for (int nt = 0; nt < 4; ++nt) {
            short8 bv0 = *(const short8*)&vT_lds[nt * 16 + l16][quad * 8];
            short8 bv1 = *(const short8*)&vT_lds[nt * 16 + l16][quad * 8 + 32];
            Oa[nt] = __builtin_amdgcn_mfma_f32_16x16x32_bf16(ap0, bv0, Oa[nt], 0, 0, 0);
            Oa[nt] = __builtin_amdgcn_mfma_f32_16x16x32_bf16(ap1, bv1, Oa[nt], 0, 0, 0);
        }

        // ---- rotate register sets ----
#pragma unroll
        for (int u = 0; u < 4; ++u) { kr[u] = kn[u]; vr[u] = vn[u]; }
#pragma unroll
        for (int u = 0; u < 16; ++u) rc_[u] = rn_[u];
    }

#pragma unroll
    for (int reg = 0; reg < 4; ++reg) {
#pragma unroll
        for (int off = 1; off < 16; off <<= 1)
            lpart[reg] += __shfl_xor(lpart[reg], off, 64);
    }

#pragma unroll
    for (int reg = 0; reg < 4; ++reg) {
        const int i = i0 + w * 16 + quad * 4 + reg;
        const bool dead = (i >= xlen + 256);
        const float linv = 1.0f / lpart[reg];
#pragma unroll
        for (int nt = 0; nt < 4; ++nt) {
            const int d = n * 64 + nt * 16 + l16;
            float val = dead ? vmean[(size_t)b * 512 + d] : Oa[nt][reg] * linv;
            out[((size_t)b * S_ + i) * 512 + d] = val;
        }
    }
}

// ---------------------------------------------------------------------------
extern "C" void kernel_launch(void* const* d_in, const int* in_sizes, int n_in,
                              void* d_out, int out_size, void* d_ws, size_t ws_size,
                              hipStream_t stream) {
    const float* x     = (const float*)d_in[0];
    const float* Wq    = (const float*)d_in[1];
    const float* b_con = (const float*)d_in[2];
    const float* b_rel = (const float*)d_in[3];
    const float* Wk    = (const float*)d_in[4];
    const float* Wkr   = (const float*)d_in[5];
    const float* Wv    = (const float*)d_in[6];
    const float* bv    = (const float*)d_in[7];
    const int*   xlen  = (const int*)d_in[8];
    float* out = (float*)d_out;

    float* ws = (float*)d_ws;
    float* vmean = ws;                       // 1024 fp32
    ushort_t* ub   = (ushort_t*)(vmean + 1024);
    ushort_t* R    = ub;                     // 2*8*2048*264 bf16
    ushort_t* qcon = R    + 8650752;         // 4096*512 bf16
    ushort_t* kbuf = qcon + 2097152;
    ushort_t* vT   = kbuf + 2097152;         // 1024 x 2048 bf16
    ushort_t* qrel = vT   + 2097152;
    ushort_t* krel = qrel + 2097152;         // 384*512 bf16
    ushort_t* pos  = krel + 196608;          // 384*512 bf16
    ushort_t* WTq  = pos  + 196608;          // 512*512 bf16 each
    ushort_t* WTk  = WTq + 262144;
    ushort_t* WTv  = WTk + 262144;
    ushort_t* WTkr = WTv + 262144;

    void* kargs[] = {
        (void*)&x, (void*)&Wq, (void*)&Wk, (void*)&Wv, (void*)&Wkr,
        (void*)&b_con, (void*)&b_rel, (void*)&bv,
        (void*)&WTq, (void*)&WTk, (void*)&WTv, (void*)&WTkr, (void*)&pos,
        (void*)&qcon, (void*)&qrel, (void*)&kbuf, (void*)&vT, (void*)&krel,
        (void*)&R, (void*)&vmean
    };
    hipError_t err = hipLaunchCooperativeKernel(
        (const void*)fused_front, dim3(512), dim3(256), kargs, 0, stream);
    if (err != hipSuccess) {
        (void)hipGetLastError();   // clear sticky state; fall back to 3 launches
        kA<<<dim3(512), 256, 0, stream>>>(Wq, Wk, Wv, Wkr,
                                          WTq, WTk, WTv, WTkr, pos);
        kB<<<dim3(512), 256, 0, stream>>>(x, WTq, WTk, WTv, pos, WTkr,
                                          b_con, b_rel, bv,
                                          qcon, qrel, kbuf, vT, krel);
        kC<<<dim3(512), 256, 0, stream>>>(qrel, krel, vT, R, vmean);
    }
    attn_kernel<<<dim3(64, 8, 2), 128, 0, stream>>>(qcon, kbuf, vT, R, vmean,
                                                    xlen, out);
}

// Round 16
// 146.628 us; speedup vs baseline: 2.7160x; 2.7160x over previous
//
#include <hip/hip_runtime.h>
#include <math.h>

#define S_ 2048
#define NH 8
#define DH 64
#define RSTRIDE 264   // padded row stride for R (r in [0,256] meaningful)
#define LP 72         // bf16 LDS row pitch: 144 B = 9*16 B -> b128-aligned

typedef __attribute__((ext_vector_type(8))) short short8;   // 8 x bf16 (4 VGPRs)
typedef __attribute__((ext_vector_type(4))) float f32x4;    // MFMA accumulator
typedef unsigned short ushort_t;

__device__ __forceinline__ short bf16r(float x) {   // RNE float->bf16
    union { float f; unsigned u; } v; v.f = x;
    unsigned r = v.u + 0x7fffu + ((v.u >> 16) & 1u);
    return (short)(r >> 16);
}
__device__ __forceinline__ float b2f(ushort_t h) {  // bf16->float
    union { float f; unsigned u; } v; v.u = ((unsigned)h) << 16; return v.f;
}

// ---------------------------------------------------------------------------
// Kernel 0: prep.  z<4: WT[n][k] = bf16(W[k][n]) (LDS-tiled 64x64).
// z==4: pos table bf16; rows 257..383 zero.
// z==5: xb16 = bf16(x)  (one-time convert; qkv re-read x >=3x in fp32 and
//        burned 16 bf16r/thread/iter in its latency-critical staging).
// ---------------------------------------------------------------------------
__global__ __launch_bounds__(256) void prep_kernel(
    const float* __restrict__ x,
    const float* __restrict__ Wq, const float* __restrict__ Wk,
    const float* __restrict__ Wv, const float* __restrict__ Wkr,
    ushort_t* __restrict__ WTq, ushort_t* __restrict__ WTk,
    ushort_t* __restrict__ WTv, ushort_t* __restrict__ WTkr,
    ushort_t* __restrict__ pos, ushort_t* __restrict__ xb16)
{
    const int widx = blockIdx.z;
    const int t = threadIdx.x;
    if (widx == 4) {
        const int base = blockIdx.y * 8 + blockIdx.x;    // 0..63
        const float C = -0.051905126482615036f;          // -log2(10000)/256
        const int f = t;
#pragma unroll
        for (int rep = 0; rep < 6; ++rep) {
            const int r = base + rep * 64;               // 0..383
            unsigned pk = 0;
            if (r <= 256) {
                float ang = (float)r * exp2f(C * (float)f);
                unsigned s = (unsigned)(ushort_t)bf16r(sinf(ang));
                unsigned c = (unsigned)(ushort_t)bf16r(cosf(ang));
                pk = s | (c << 16);
            }
            ((unsigned*)pos)[(size_t)r * 256 + f] = pk;
        }
        return;
    }
    if (widx == 5) {
        // 64 blocks: each converts 32768 contiguous elements of x.
        const int sub = blockIdx.y * 8 + blockIdx.x;     // 0..63
        const size_t base = (size_t)sub * 32768;
#pragma unroll
        for (int it = 0; it < 8; ++it) {
            const size_t idx = base + (size_t)it * 4096 + (size_t)t * 16;
            const float* src = &x[idx];
            ushort_t t16[16];
#pragma unroll
            for (int u = 0; u < 16; ++u) t16[u] = (ushort_t)bf16r(src[u]);
            *(short8*)&xb16[idx]     = *(short8*)&t16[0];
            *(short8*)&xb16[idx + 8] = *(short8*)&t16[8];
        }
        return;
    }
    const float* W = (widx == 0) ? Wq : (widx == 1) ? Wk : (widx == 2) ? Wv : Wkr;
    ushort_t* WT   = (widx == 0) ? WTq : (widx == 1) ? WTk : (widx == 2) ? WTv : WTkr;
    const int k0 = blockIdx.x * 64, n0 = blockIdx.y * 64;
    __shared__ __align__(16) ushort_t T[64][72];
    const int srow = t >> 2, sc0 = (t & 3) * 16;
    const float* src = &W[(size_t)(k0 + srow) * 512 + n0 + sc0];
#pragma unroll
    for (int u = 0; u < 16; ++u) T[sc0 + u][srow] = (ushort_t)bf16r(src[u]);
    __syncthreads();
    ushort_t* dst = &WT[(size_t)(n0 + srow) * 512 + k0 + sc0];
    *(short8*)dst       = *(const short8*)&T[srow][sc0];
    *(short8*)(dst + 8) = *(const short8*)&T[srow][sc0 + 8];
}

// ---------------------------------------------------------------------------
// Kernel 1: fused QKV (+krel) GEMM via bf16 MFMA.  Grid (32, 25).
// by>>3 = 0: qcon/qrel; 1: k; 2: V^T; by==24: krel = pos @ Wkr.
// All operands now pre-converted bf16 -> staging is pure short8 copies,
// register-prefetched one K-iter ahead (R13 pipeline).
// ---------------------------------------------------------------------------
__global__ __launch_bounds__(256) void qkv_gemm(
    const ushort_t* __restrict__ xb16,
    const ushort_t* __restrict__ WTq, const ushort_t* __restrict__ WTk,
    const ushort_t* __restrict__ WTv,
    const ushort_t* __restrict__ pos, const ushort_t* __restrict__ WTkr,
    const float* __restrict__ b_con, const float* __restrict__ b_rel,
    const float* __restrict__ bv,
    ushort_t* __restrict__ qcon, ushort_t* __restrict__ qrel,
    ushort_t* __restrict__ kout, ushort_t* __restrict__ vT,
    ushort_t* __restrict__ krel)
{
    const int widx = blockIdx.y >> 3;
    const int tid = threadIdx.x, lane = tid & 63, w = tid >> 6;
    const int quad = lane >> 4, l16 = lane & 15;

    __shared__ __align__(16) ushort_t A_lds[128][40];
    __shared__ __align__(16) ushort_t B_lds[64][40];

    f32x4 acc[2][4];
#pragma unroll
    for (int mt = 0; mt < 2; ++mt)
#pragma unroll
        for (int nt = 0; nt < 4; ++nt) acc[mt][nt] = (f32x4){0.f, 0.f, 0.f, 0.f};

    const int arow = tid >> 1, ak0 = (tid & 1) * 16;
    const int brow = tid >> 2, bk0 = (tid & 3) * 8;

    if (widx < 2) {
        const int m0 = blockIdx.x * 128;
        const int n0 = (blockIdx.y & 7) * 64;
        const ushort_t* WT = (widx == 0) ? WTq : WTk;
        const ushort_t* xrow = &xb16[(size_t)(m0 + arow) * 512 + ak0];
        const ushort_t* wrow = &WT[(size_t)(n0 + brow) * 512 + bk0];

        short8 pa0 = *(const short8*)xrow;
        short8 pa1 = *(const short8*)(xrow + 8);
        short8 pb  = *(const short8*)wrow;

#pragma unroll 1
        for (int k0 = 0; k0 < 512; k0 += 32) {
            __syncthreads();   // prev iter's MFMA LDS reads done
            *(short8*)&A_lds[arow][ak0]     = pa0;
            *(short8*)&A_lds[arow][ak0 + 8] = pa1;
            *(short8*)&B_lds[brow][bk0]     = pb;
            if (k0 < 480) {
                pa0 = *(const short8*)(xrow + k0 + 32);
                pa1 = *(const short8*)(xrow + k0 + 40);
                pb  = *(const short8*)(wrow + k0 + 32);
            }
            __syncthreads();
            short8 a0 = *(const short8*)&A_lds[w * 32 + l16][quad * 8];
            short8 a1 = *(const short8*)&A_lds[w * 32 + 16 + l16][quad * 8];
#pragma unroll
            for (int nt = 0; nt < 4; ++nt) {
                short8 bb = *(const short8*)&B_lds[nt * 16 + l16][quad * 8];
                acc[0][nt] = __builtin_amdgcn_mfma_f32_16x16x32_bf16(a0, bb, acc[0][nt], 0, 0, 0);
                acc[1][nt] = __builtin_amdgcn_mfma_f32_16x16x32_bf16(a1, bb, acc[1][nt], 0, 0, 0);
            }
        }

#pragma unroll
        for (int nt = 0; nt < 4; ++nt) {
            const int col = n0 + nt * 16 + l16;
            float bc = 0.f, br = 0.f;
            if (widx == 0) { bc = b_con[col]; br = b_rel[col]; }
#pragma unroll
            for (int mt = 0; mt < 2; ++mt) {
#pragma unroll
                for (int reg = 0; reg < 4; ++reg) {
                    const size_t m = (size_t)(m0 + w * 32 + mt * 16 + quad * 4 + reg);
                    const float val = acc[mt][nt][reg];
                    if (widx == 0) {
                        qcon[m * 512 + col] = (ushort_t)bf16r((val + bc) * 0.125f);
                        qrel[m * 512 + col] = (ushort_t)bf16r((val + br) * 0.125f);
                    } else {
                        kout[m * 512 + col] = (ushort_t)bf16r(val);
                    }
                }
            }
        }
    } else if (widx == 2) {
        // ---- V transposed mode: vT[d][j] = WTv[d] . x[j] + bv ----
        const int vb = (blockIdx.y & 7) * 32 + blockIdx.x;   // 0..255
        const int m0d = (vb & 3) * 128;                      // d tile
        const int n0j = (vb >> 2) * 64;                      // seq tile
        const ushort_t* wrow = &WTv[(size_t)(m0d + arow) * 512 + ak0];
        const ushort_t* xrow = &xb16[(size_t)(n0j + brow) * 512 + bk0];

        short8 pa0 = *(const short8*)wrow;
        short8 pa1 = *(const short8*)(wrow + 8);
        short8 pb  = *(const short8*)xrow;

#pragma unroll 1
        for (int k0 = 0; k0 < 512; k0 += 32) {
            __syncthreads();
            *(short8*)&A_lds[arow][ak0]     = pa0;
            *(short8*)&A_lds[arow][ak0 + 8] = pa1;
            *(short8*)&B_lds[brow][bk0]     = pb;
            if (k0 < 480) {
                pa0 = *(const short8*)(wrow + k0 + 32);
                pa1 = *(const short8*)(wrow + k0 + 40);
                pb  = *(const short8*)(xrow + k0 + 32);
            }
            __syncthreads();
            short8 a0 = *(const short8*)&A_lds[w * 32 + l16][quad * 8];
            short8 a1 = *(const short8*)&A_lds[w * 32 + 16 + l16][quad * 8];
#pragma unroll
            for (int nt = 0; nt < 4; ++nt) {
                short8 bb = *(const short8*)&B_lds[nt * 16 + l16][quad * 8];
                acc[0][nt] = __builtin_amdgcn_mfma_f32_16x16x32_bf16(a0, bb, acc[0][nt], 0, 0, 0);
                acc[1][nt] = __builtin_amdgcn_mfma_f32_16x16x32_bf16(a1, bb, acc[1][nt], 0, 0, 0);
            }
        }

        const int b = n0j >> 11;
#pragma unroll
        for (int mt = 0; mt < 2; ++mt) {
#pragma unroll
            for (int reg = 0; reg < 4; ++reg) {
                const int d = m0d + w * 32 + mt * 16 + quad * 4 + reg;  // 0..511
                const int n = d >> 6, dd = d & 63;
                const float bvv = bv[d];
#pragma unroll
                for (int nt = 0; nt < 4; ++nt) {
                    const int s = (n0j + nt * 16 + l16) & 2047;
                    vT[((size_t)((b * NH + n) * 64 + dd)) * 2048 + s] =
                        (ushort_t)bf16r(acc[mt][nt][reg] + bvv);
                }
            }
        }
    } else {
        // ---- krel mode (by == 24): krel = pos @ Wkr ----
        if (blockIdx.x >= 24) return;
        const int m0 = (blockIdx.x >> 3) * 128;              // 0..255
        const int n0 = (blockIdx.x & 7) * 64;
        const ushort_t* prow = &pos[(size_t)(m0 + arow) * 512 + ak0];
        const ushort_t* wrow = &WTkr[(size_t)(n0 + brow) * 512 + bk0];

        short8 pa0 = *(const short8*)prow;
        short8 pa1 = *(const short8*)(prow + 8);
        short8 pb  = *(const short8*)wrow;

#pragma unroll 1
        for (int k0 = 0; k0 < 512; k0 += 32) {
            __syncthreads();
            *(short8*)&A_lds[arow][ak0]     = pa0;
            *(short8*)&A_lds[arow][ak0 + 8] = pa1;
            *(short8*)&B_lds[brow][bk0]     = pb;
            if (k0 < 480) {
                pa0 = *(const short8*)(prow + k0 + 32);
                pa1 = *(const short8*)(prow + k0 + 40);
                pb  = *(const short8*)(wrow + k0 + 32);
            }
            __syncthreads();
            short8 a0 = *(const short8*)&A_lds[w * 32 + l16][quad * 8];
            short8 a1 = *(const short8*)&A_lds[w * 32 + 16 + l16][quad * 8];
#pragma unroll
            for (int nt = 0; nt < 4; ++nt) {
                short8 bb = *(const short8*)&B_lds[nt * 16 + l16][quad * 8];
                acc[0][nt] = __builtin_amdgcn_mfma_f32_16x16x32_bf16(a0, bb, acc[0][nt], 0, 0, 0);
                acc[1][nt] = __builtin_amdgcn_mfma_f32_16x16x32_bf16(a1, bb, acc[1][nt], 0, 0, 0);
            }
        }

#pragma unroll
        for (int nt = 0; nt < 4; ++nt) {
            const int col = n0 + nt * 16 + l16;
#pragma unroll
            for (int mt = 0; mt < 2; ++mt)
#pragma unroll
                for (int reg = 0; reg < 4; ++reg) {
                    const size_t m = (size_t)(m0 + w * 32 + mt * 16 + quad * 4 + reg);
                    krel[m * 512 + col] = (ushort_t)bf16r(acc[mt][nt][reg]);
                }
        }
    }
}

// ---------------------------------------------------------------------------
// Kernel 3: R[b,n,i,r] bf16 = qrel . krel  (scale in qrel).  Grid (17,8,2):
// tile<16 = GEMM (B chunks register-prefetched); tile==16 = vmean fold.
// ---------------------------------------------------------------------------
__global__ __launch_bounds__(256) void rel_gemm(
    const ushort_t* __restrict__ qrel, const ushort_t* __restrict__ krel,
    const ushort_t* __restrict__ vT, ushort_t* __restrict__ R,
    float* __restrict__ vmean)
{
    const int tile = blockIdx.x, n = blockIdx.y, b = blockIdx.z;
    const int tid = threadIdx.x, lane = tid & 63, w = tid >> 6;
    const int quad = lane >> 4, l16 = lane & 15;

    __shared__ __align__(16) ushort_t A_lds[128][LP];
    __shared__ __align__(16) ushort_t B_lds[64][LP];

    if (tile == 16) {
        // ---- vmean: rows (b*8+n)*64 + d of vT, mean over 2048 ----
        const int row = tid >> 2, seg = tid & 3;
        const ushort_t* src = &vT[((size_t)((b * NH + n) * 64 + row)) * 2048 + seg * 512];
        float sum = 0.f;
        for (int it = 0; it < 64; ++it) {
            short8 h = *(const short8*)(src + it * 8);
#pragma unroll
            for (int u = 0; u < 8; ++u) sum += b2f((ushort_t)h[u]);
        }
        float* scratch = (float*)A_lds;
        scratch[row * 4 + seg] = sum;
        __syncthreads();
        if (tid < 64) {
            float s = scratch[tid * 4] + scratch[tid * 4 + 1]
                    + scratch[tid * 4 + 2] + scratch[tid * 4 + 3];
            vmean[(size_t)b * 512 + n * 64 + tid] = s * (1.0f / (float)S_);
        }
        return;
    }

    const int i0 = tile * 128;
    {
        const int srow = tid >> 1, sc0 = (tid & 1) * 32;
        const ushort_t* src = &qrel[((size_t)b * S_ + i0 + srow) * 512 + n * 64 + sc0];
#pragma unroll
        for (int u = 0; u < 4; ++u)
            *(short8*)&A_lds[srow][sc0 + u * 8] = *(const short8*)(src + u * 8);
    }

    const size_t rbase = ((size_t)(b * NH + n) * S_ + i0) * RSTRIDE;
    const int srow2 = tid >> 2, sc2 = (tid & 3) * 16;

    short8 pb0, pb1;
    auto issueB = [&](int rc) {
        const ushort_t* src = &krel[(size_t)(rc * 64 + srow2) * 512 + n * 64 + sc2];
        pb0 = *(const short8*)src;
        pb1 = *(const short8*)(src + 8);
    };
    issueB(0);

#pragma unroll 1
    for (int rc = 0; rc < 5; ++rc) {
        __syncthreads();   // A visible (rc==0) / prev chunk's B reads done
        *(short8*)&B_lds[srow2][sc2]     = pb0;
        *(short8*)&B_lds[srow2][sc2 + 8] = pb1;
        if (rc < 4) issueB(rc + 1);
        __syncthreads();

        short8 a[2][2];
#pragma unroll
        for (int mt = 0; mt < 2; ++mt) {
            a[mt][0] = *(const short8*)&A_lds[w * 32 + mt * 16 + l16][quad * 8];
            a[mt][1] = *(const short8*)&A_lds[w * 32 + mt * 16 + l16][quad * 8 + 32];
        }
#pragma unroll
        for (int nt = 0; nt < 4; ++nt) {
            short8 b0 = *(const short8*)&B_lds[nt * 16 + l16][quad * 8];
            short8 b1 = *(const short8*)&B_lds[nt * 16 + l16][quad * 8 + 32];
            const int r = rc * 64 + nt * 16 + l16;
#pragma unroll
            for (int mt = 0; mt < 2; ++mt) {
                f32x4 s = (f32x4){0.f, 0.f, 0.f, 0.f};
                s = __builtin_amdgcn_mfma_f32_16x16x32_bf16(a[mt][0], b0, s, 0, 0, 0);
                s = __builtin_amdgcn_mfma_f32_16x16x32_bf16(a[mt][1], b1, s, 0, 0, 0);
                if (r < RSTRIDE) {
#pragma unroll
                    for (int reg = 0; reg < 4; ++reg) {
                        const int i = w * 32 + mt * 16 + quad * 4 + reg;
                        R[rbase + (size_t)i * RSTRIDE + r] = (ushort_t)bf16r(s[reg]);
                    }
                }
            }
        }
    }
}

// ---------------------------------------------------------------------------
// Kernel 5: banded attention via bf16 MFMA, batched softmax without max
// subtraction.  R13 structure verbatim (best verified): register prefetch of
// next chunk's k/vT/R, rolled loop, 27.6 KB LDS -> 5 blocks/CU, XCD swizzle.
// ---------------------------------------------------------------------------
__global__ __launch_bounds__(128) void attn_kernel(
    const ushort_t* __restrict__ qcon, const ushort_t* __restrict__ kbuf,
    const ushort_t* __restrict__ vT, const ushort_t* __restrict__ R,
    const float* __restrict__ vmean, const int* __restrict__ xlen_p,
    float* __restrict__ out)
{
    const int bx = blockIdx.x;
    const int tile = ((bx & 7) << 3) | (bx >> 3);   // XCD swizzle
    const int n = blockIdx.y, b = blockIdx.z;
    const int i0 = tile * 32;
    const int tid = threadIdx.x, lane = tid & 63, w = tid >> 6;
    const int quad = lane >> 4, l16 = lane & 15;
    const int xlen = xlen_p[b];

    __shared__ __align__(16) ushort_t q_lds[32][LP];
    __shared__ __align__(16) ushort_t k_lds[64][LP];
    __shared__ __align__(16) ushort_t vT_lds[64][LP];
    __shared__ __align__(16) ushort_t p_lds[32][LP];

    {
        const int qr = tid >> 2, qc = (tid & 3) * 16;
        const ushort_t* src = &qcon[((size_t)b * S_ + i0 + qr) * 512 + n * 64 + qc];
        *(short8*)&q_lds[qr][qc]     = *(const short8*)src;
        *(short8*)&q_lds[qr][qc + 8] = *(const short8*)(src + 8);
    }

    f32x4 Oa[4];
#pragma unroll
    for (int nt = 0; nt < 4; ++nt) Oa[nt] = (f32x4){0.f, 0.f, 0.f, 0.f};
    float lpart[4] = {};

    const size_t rrowB = (size_t)(b * NH + n) * S_ * RSTRIDE;
    const size_t vTbase = (size_t)((b * NH + n) * 64) * 2048;
    const int srow = tid >> 1, sc0 = (tid & 1) * 32;
    const short8 z8 = {0, 0, 0, 0, 0, 0, 0, 0};

    short8 kr[4], vr[4], kn[4], vn[4];
    ushort_t rc_[16], rn_[16];

    auto issue = [&](int c, short8* kd, short8* vd, ushort_t* rd) {
        const int jc0 = i0 - 256 + c * 64;
        const int jg = jc0 + srow;
        const bool okk = (jg >= 0);
        const ushort_t* ks = &kbuf[((size_t)b * S_ + jg) * 512 + n * 64 + sc0];
        const ushort_t* vs = &vT[vTbase + (size_t)srow * 2048 + jc0 + sc0];
#pragma unroll
        for (int u = 0; u < 4; ++u) {
            kd[u] = okk ? *(const short8*)(ks + u * 8) : z8;
            const bool okv = (jc0 + sc0 + u * 8) >= 0;
            vd[u] = okv ? *(const short8*)(vs + u * 8) : z8;
        }
#pragma unroll
        for (int jt = 0; jt < 4; ++jt) {
#pragma unroll
            for (int reg = 0; reg < 4; ++reg) {
                const int i = i0 + w * 16 + quad * 4 + reg;
                const int j = jc0 + jt * 16 + l16;
                const int r = i - j;
                const bool valid = (j >= 0) && (j < xlen) && (r >= 0) && (r <= 256);
                rd[jt * 4 + reg] = valid ? R[rrowB + (size_t)i * RSTRIDE + r]
                                         : (ushort_t)0;
            }
        }
    };

    issue(0, kr, vr, rc_);

#pragma unroll 1
    for (int c = 0; c < 5; ++c) {
        const int jc0 = i0 - 256 + c * 64;
        __syncthreads();   // prev-chunk PV reads of k/vT/p done
#pragma unroll
        for (int u = 0; u < 4; ++u) {
            *(short8*)&k_lds[srow][sc0 + u * 8]  = kr[u];
            *(short8*)&vT_lds[srow][sc0 + u * 8] = vr[u];
        }
        if (c < 4) issue(c + 1, kn, vn, rn_);
        __syncthreads();

        // ---- QK ----
        short8 aq0 = *(const short8*)&q_lds[w * 16 + l16][quad * 8];
        short8 aq1 = *(const short8*)&q_lds[w * 16 + l16][quad * 8 + 32];
        f32x4 Sacc[4];
#pragma unroll
        for (int jt = 0; jt < 4; ++jt) {
            short8 bk0 = *(const short8*)&k_lds[jt * 16 + l16][quad * 8];
            short8 bk1 = *(const short8*)&k_lds[jt * 16 + l16][quad * 8 + 32];
            f32x4 s = (f32x4){0.f, 0.f, 0.f, 0.f};
            s = __builtin_amdgcn_mfma_f32_16x16x32_bf16(aq0, bk0, s, 0, 0, 0);
            s = __builtin_amdgcn_mfma_f32_16x16x32_bf16(aq1, bk1, s, 0, 0, 0);
            Sacc[jt] = s;
        }

        // ---- mask + rel bias + exp; p -> LDS bf16 ----
#pragma unroll
        for (int jt = 0; jt < 4; ++jt) {
#pragma unroll
            for (int reg = 0; reg < 4; ++reg) {
                const int i = i0 + w * 16 + quad * 4 + reg;
                const int j = jc0 + jt * 16 + l16;
                const int r = i - j;
                const bool valid = (j >= 0) && (j < xlen) && (r >= 0) && (r <= 256);
                float e = valid ? __expf(Sacc[jt][reg] + b2f(rc_[jt * 4 + reg])) : 0.f;
                lpart[reg] += e;
                p_lds[w * 16 + quad * 4 + reg][jt * 16 + l16] = (ushort_t)bf16r(e);
            }
        }
        __syncthreads();

        // ---- PV ----
        short8 ap0 = *(const short8*)&p_lds[w * 16 + l16][quad * 8];
        short8 ap1 = *(const short8*)&p_lds[w * 16 + l16][quad * 8 + 32];
#pragma unroll
        for (int nt = 0; nt < 4; ++nt) {
            short8 bv0 = *(const short8*)&vT_lds[nt * 16 + l16][quad * 8];
            short8 bv1 = *(const short8*)&vT_lds[nt * 16 + l16][quad * 8 + 32];
            Oa[nt] = __builtin_amdgcn_mfma_f32_16x16x32_bf16(ap0, bv0, Oa[nt], 0, 0, 0);
            Oa[nt] = __builtin_amdgcn_mfma_f32_16x16x32_bf16(ap1, bv1, Oa[nt], 0, 0, 0);
        }

        // ---- rotate register sets ----
#pragma unroll
        for (int u = 0; u < 4; ++u) { kr[u] = kn[u]; vr[u] = vn[u]; }
#pragma unroll
        for (int u = 0; u < 16; ++u) rc_[u] = rn_[u];
    }

#pragma unroll
    for (int reg = 0; reg < 4; ++reg) {
#pragma unroll
        for (int off = 1; off < 16; off <<= 1)
            lpart[reg] += __shfl_xor(lpart[reg], off, 64);
    }

#pragma unroll
    for (int reg = 0; reg < 4; ++reg) {
        const int i = i0 + w * 16 + quad * 4 + reg;
        const bool dead = (i >= xlen + 256);
        const float linv = 1.0f / lpart[reg];
#pragma unroll
        for (int nt = 0; nt < 4; ++nt) {
            const int d = n * 64 + nt * 16 + l16;
            float val = dead ? vmean[(size_t)b * 512 + d] : Oa[nt][reg] * linv;
            out[((size_t)b * S_ + i) * 512 + d] = val;
        }
    }
}

// ---------------------------------------------------------------------------
extern "C" void kernel_launch(void* const* d_in, const int* in_sizes, int n_in,
                              void* d_out, int out_size, void* d_ws, size_t ws_size,
                              hipStream_t stream) {
    const float* x     = (const float*)d_in[0];
    const float* Wq    = (const float*)d_in[1];
    const float* b_con = (const float*)d_in[2];
    const float* b_rel = (const float*)d_in[3];
    const float* Wk    = (const float*)d_in[4];
    const float* Wkr   = (const float*)d_in[5];
    const float* Wv    = (const float*)d_in[6];
    const float* bv    = (const float*)d_in[7];
    const int*   xlen  = (const int*)d_in[8];
    float* out = (float*)d_out;

    float* ws = (float*)d_ws;
    float* vmean = ws;                       // 1024 fp32
    ushort_t* ub   = (ushort_t*)(vmean + 1024);
    ushort_t* R    = ub;                     // 2*8*2048*264 bf16
    ushort_t* qcon = R    + 8650752;         // 4096*512 bf16
    ushort_t* kbuf = qcon + 2097152;
    ushort_t* vT   = kbuf + 2097152;         // 1024 x 2048 bf16
    ushort_t* qrel = vT   + 2097152;
    ushort_t* xb16 = qrel + 2097152;         // 4096*512 bf16
    ushort_t* krel = xb16 + 2097152;         // 384*512 bf16
    ushort_t* pos  = krel + 196608;          // 384*512 bf16
    ushort_t* WTq  = pos  + 196608;          // 512*512 bf16 each
    ushort_t* WTk  = WTq + 262144;
    ushort_t* WTv  = WTk + 262144;
    ushort_t* WTkr = WTv + 262144;

    prep_kernel<<<dim3(8, 8, 6), 256, 0, stream>>>(x, Wq, Wk, Wv, Wkr,
                                                   WTq, WTk, WTv, WTkr, pos, xb16);
    qkv_gemm<<<dim3(32, 25), 256, 0, stream>>>(xb16, WTq, WTk, WTv, pos, WTkr,
                                               b_con, b_rel, bv,
                                               qcon, qrel, kbuf, vT, krel);
    rel_gemm<<<dim3(17, 8, 2), 256, 0, stream>>>(qrel, krel, vT, R, vmean);
    attn_kernel<<<dim3(64, 8, 2), 128, 0, stream>>>(qcon, kbuf, vT, R, vmean,
                                                    xlen, out);
}

// Round 17
// 135.081 us; speedup vs baseline: 2.9482x; 1.0855x over previous
//
#include <hip/hip_runtime.h>
#include <math.h>

#define S_ 2048
#define NH 8
#define DH 64
#define CSL 320       // R3 slots per row: cslot = j - (i&~31) + 256 in [0,320)
#define LP 72         // bf16 LDS row pitch: 144 B = 9*16 B -> b128-aligned

typedef __attribute__((ext_vector_type(8))) short short8;   // 8 x bf16 (4 VGPRs)
typedef __attribute__((ext_vector_type(4))) float f32x4;    // MFMA accumulator
typedef unsigned short ushort_t;

__device__ __forceinline__ short bf16r(float x) {   // RNE float->bf16
    union { float f; unsigned u; } v; v.f = x;
    unsigned r = v.u + 0x7fffu + ((v.u >> 16) & 1u);
    return (short)(r >> 16);
}
__device__ __forceinline__ float b2f(ushort_t h) {  // bf16->float
    union { float f; unsigned u; } v; v.u = ((unsigned)h) << 16; return v.f;
}

// ---------------------------------------------------------------------------
// Kernel 0: prep.  z<4: WT[n][k] = bf16(W[k][n]) (LDS-tiled 64x64).
// z==4: pos table bf16; rows 257..383 zero.  z==5: xb16 = bf16(x).
// ---------------------------------------------------------------------------
__global__ __launch_bounds__(256) void prep_kernel(
    const float* __restrict__ x,
    const float* __restrict__ Wq, const float* __restrict__ Wk,
    const float* __restrict__ Wv, const float* __restrict__ Wkr,
    ushort_t* __restrict__ WTq, ushort_t* __restrict__ WTk,
    ushort_t* __restrict__ WTv, ushort_t* __restrict__ WTkr,
    ushort_t* __restrict__ pos, ushort_t* __restrict__ xb16)
{
    const int widx = blockIdx.z;
    const int t = threadIdx.x;
    if (widx == 4) {
        const int base = blockIdx.y * 8 + blockIdx.x;    // 0..63
        const float C = -0.051905126482615036f;          // -log2(10000)/256
        const int f = t;
#pragma unroll
        for (int rep = 0; rep < 6; ++rep) {
            const int r = base + rep * 64;               // 0..383
            unsigned pk = 0;
            if (r <= 256) {
                float ang = (float)r * exp2f(C * (float)f);
                unsigned s = (unsigned)(ushort_t)bf16r(sinf(ang));
                unsigned c = (unsigned)(ushort_t)bf16r(cosf(ang));
                pk = s | (c << 16);
            }
            ((unsigned*)pos)[(size_t)r * 256 + f] = pk;
        }
        return;
    }
    if (widx == 5) {
        const int sub = blockIdx.y * 8 + blockIdx.x;     // 0..63
        const size_t base = (size_t)sub * 32768;
#pragma unroll
        for (int it = 0; it < 8; ++it) {
            const size_t idx = base + (size_t)it * 4096 + (size_t)t * 16;
            const float* src = &x[idx];
            ushort_t t16[16];
#pragma unroll
            for (int u = 0; u < 16; ++u) t16[u] = (ushort_t)bf16r(src[u]);
            *(short8*)&xb16[idx]     = *(short8*)&t16[0];
            *(short8*)&xb16[idx + 8] = *(short8*)&t16[8];
        }
        return;
    }
    const float* W = (widx == 0) ? Wq : (widx == 1) ? Wk : (widx == 2) ? Wv : Wkr;
    ushort_t* WT   = (widx == 0) ? WTq : (widx == 1) ? WTk : (widx == 2) ? WTv : WTkr;
    const int k0 = blockIdx.x * 64, n0 = blockIdx.y * 64;
    __shared__ __align__(16) ushort_t T[64][72];
    const int srow = t >> 2, sc0 = (t & 3) * 16;
    const float* src = &W[(size_t)(k0 + srow) * 512 + n0 + sc0];
#pragma unroll
    for (int u = 0; u < 16; ++u) T[sc0 + u][srow] = (ushort_t)bf16r(src[u]);
    __syncthreads();
    ushort_t* dst = &WT[(size_t)(n0 + srow) * 512 + k0 + sc0];
    *(short8*)dst       = *(const short8*)&T[srow][sc0];
    *(short8*)(dst + 8) = *(const short8*)&T[srow][sc0 + 8];
}

// ---------------------------------------------------------------------------
// Kernel 1: fused QKV (+krel) GEMM via bf16 MFMA.  Grid (32, 25).  R16 body.
// ---------------------------------------------------------------------------
__global__ __launch_bounds__(256) void qkv_gemm(
    const ushort_t* __restrict__ xb16,
    const ushort_t* __restrict__ WTq, const ushort_t* __restrict__ WTk,
    const ushort_t* __restrict__ WTv,
    const ushort_t* __restrict__ pos, const ushort_t* __restrict__ WTkr,
    const float* __restrict__ b_con, const float* __restrict__ b_rel,
    const float* __restrict__ bv,
    ushort_t* __restrict__ qcon, ushort_t* __restrict__ qrel,
    ushort_t* __restrict__ kout, ushort_t* __restrict__ vT,
    ushort_t* __restrict__ krel)
{
    const int widx = blockIdx.y >> 3;
    const int tid = threadIdx.x, lane = tid & 63, w = tid >> 6;
    const int quad = lane >> 4, l16 = lane & 15;

    __shared__ __align__(16) ushort_t A_lds[128][40];
    __shared__ __align__(16) ushort_t B_lds[64][40];

    f32x4 acc[2][4];
#pragma unroll
    for (int mt = 0; mt < 2; ++mt)
#pragma unroll
        for (int nt = 0; nt < 4; ++nt) acc[mt][nt] = (f32x4){0.f, 0.f, 0.f, 0.f};

    const int arow = tid >> 1, ak0 = (tid & 1) * 16;
    const int brow = tid >> 2, bk0 = (tid & 3) * 8;

    if (widx < 2) {
        const int m0 = blockIdx.x * 128;
        const int n0 = (blockIdx.y & 7) * 64;
        const ushort_t* WT = (widx == 0) ? WTq : WTk;
        const ushort_t* xrow = &xb16[(size_t)(m0 + arow) * 512 + ak0];
        const ushort_t* wrow = &WT[(size_t)(n0 + brow) * 512 + bk0];

        short8 pa0 = *(const short8*)xrow;
        short8 pa1 = *(const short8*)(xrow + 8);
        short8 pb  = *(const short8*)wrow;

#pragma unroll 1
        for (int k0 = 0; k0 < 512; k0 += 32) {
            __syncthreads();   // prev iter's MFMA LDS reads done
            *(short8*)&A_lds[arow][ak0]     = pa0;
            *(short8*)&A_lds[arow][ak0 + 8] = pa1;
            *(short8*)&B_lds[brow][bk0]     = pb;
            if (k0 < 480) {
                pa0 = *(const short8*)(xrow + k0 + 32);
                pa1 = *(const short8*)(xrow + k0 + 40);
                pb  = *(const short8*)(wrow + k0 + 32);
            }
            __syncthreads();
            short8 a0 = *(const short8*)&A_lds[w * 32 + l16][quad * 8];
            short8 a1 = *(const short8*)&A_lds[w * 32 + 16 + l16][quad * 8];
#pragma unroll
            for (int nt = 0; nt < 4; ++nt) {
                short8 bb = *(const short8*)&B_lds[nt * 16 + l16][quad * 8];
                acc[0][nt] = __builtin_amdgcn_mfma_f32_16x16x32_bf16(a0, bb, acc[0][nt], 0, 0, 0);
                acc[1][nt] = __builtin_amdgcn_mfma_f32_16x16x32_bf16(a1, bb, acc[1][nt], 0, 0, 0);
            }
        }

#pragma unroll
        for (int nt = 0; nt < 4; ++nt) {
            const int col = n0 + nt * 16 + l16;
            float bc = 0.f, br = 0.f;
            if (widx == 0) { bc = b_con[col]; br = b_rel[col]; }
#pragma unroll
            for (int mt = 0; mt < 2; ++mt) {
#pragma unroll
                for (int reg = 0; reg < 4; ++reg) {
                    const size_t m = (size_t)(m0 + w * 32 + mt * 16 + quad * 4 + reg);
                    const float val = acc[mt][nt][reg];
                    if (widx == 0) {
                        qcon[m * 512 + col] = (ushort_t)bf16r((val + bc) * 0.125f);
                        qrel[m * 512 + col] = (ushort_t)bf16r((val + br) * 0.125f);
                    } else {
                        kout[m * 512 + col] = (ushort_t)bf16r(val);
                    }
                }
            }
        }
    } else if (widx == 2) {
        // ---- V transposed mode: vT[d][j] = WTv[d] . x[j] + bv ----
        const int vb = (blockIdx.y & 7) * 32 + blockIdx.x;   // 0..255
        const int m0d = (vb & 3) * 128;                      // d tile
        const int n0j = (vb >> 2) * 64;                      // seq tile
        const ushort_t* wrow = &WTv[(size_t)(m0d + arow) * 512 + ak0];
        const ushort_t* xrow = &xb16[(size_t)(n0j + brow) * 512 + bk0];

        short8 pa0 = *(const short8*)wrow;
        short8 pa1 = *(const short8*)(wrow + 8);
        short8 pb  = *(const short8*)xrow;

#pragma unroll 1
        for (int k0 = 0; k0 < 512; k0 += 32) {
            __syncthreads();
            *(short8*)&A_lds[arow][ak0]     = pa0;
            *(short8*)&A_lds[arow][ak0 + 8] = pa1;
            *(short8*)&B_lds[brow][bk0]     = pb;
            if (k0 < 480) {
                pa0 = *(const short8*)(wrow + k0 + 32);
                pa1 = *(const short8*)(wrow + k0 + 40);
                pb  = *(const short8*)(xrow + k0 + 32);
            }
            __syncthreads();
            short8 a0 = *(const short8*)&A_lds[w * 32 + l16][quad * 8];
            short8 a1 = *(const short8*)&A_lds[w * 32 + 16 + l16][quad * 8];
#pragma unroll
            for (int nt = 0; nt < 4; ++nt) {
                short8 bb = *(const short8*)&B_lds[nt * 16 + l16][quad * 8];
                acc[0][nt] = __builtin_amdgcn_mfma_f32_16x16x32_bf16(a0, bb, acc[0][nt], 0, 0, 0);
                acc[1][nt] = __builtin_amdgcn_mfma_f32_16x16x32_bf16(a1, bb, acc[1][nt], 0, 0, 0);
            }
        }

        const int b = n0j >> 11;
#pragma unroll
        for (int mt = 0; mt < 2; ++mt) {
#pragma unroll
            for (int reg = 0; reg < 4; ++reg) {
                const int d = m0d + w * 32 + mt * 16 + quad * 4 + reg;  // 0..511
                const int n = d >> 6, dd = d & 63;
                const float bvv = bv[d];
#pragma unroll
                for (int nt = 0; nt < 4; ++nt) {
                    const int s = (n0j + nt * 16 + l16) & 2047;
                    vT[((size_t)((b * NH + n) * 64 + dd)) * 2048 + s] =
                        (ushort_t)bf16r(acc[mt][nt][reg] + bvv);
                }
            }
        }
    } else {
        // ---- krel mode (by == 24): krel = pos @ Wkr ----
        if (blockIdx.x >= 24) return;
        const int m0 = (blockIdx.x >> 3) * 128;              // 0..255
        const int n0 = (blockIdx.x & 7) * 64;
        const ushort_t* prow = &pos[(size_t)(m0 + arow) * 512 + ak0];
        const ushort_t* wrow = &WTkr[(size_t)(n0 + brow) * 512 + bk0];

        short8 pa0 = *(const short8*)prow;
        short8 pa1 = *(const short8*)(prow + 8);
        short8 pb  = *(const short8*)wrow;

#pragma unroll 1
        for (int k0 = 0; k0 < 512; k0 += 32) {
            __syncthreads();
            *(short8*)&A_lds[arow][ak0]     = pa0;
            *(short8*)&A_lds[arow][ak0 + 8] = pa1;
            *(short8*)&B_lds[brow][bk0]     = pb;
            if (k0 < 480) {
                pa0 = *(const short8*)(prow + k0 + 32);
                pa1 = *(const short8*)(prow + k0 + 40);
                pb  = *(const short8*)(wrow + k0 + 32);
            }
            __syncthreads();
            short8 a0 = *(const short8*)&A_lds[w * 32 + l16][quad * 8];
            short8 a1 = *(const short8*)&A_lds[w * 32 + 16 + l16][quad * 8];
#pragma unroll
            for (int nt = 0; nt < 4; ++nt) {
                short8 bb = *(const short8*)&B_lds[nt * 16 + l16][quad * 8];
                acc[0][nt] = __builtin_amdgcn_mfma_f32_16x16x32_bf16(a0, bb, acc[0][nt], 0, 0, 0);
                acc[1][nt] = __builtin_amdgcn_mfma_f32_16x16x32_bf16(a1, bb, acc[1][nt], 0, 0, 0);
            }
        }

#pragma unroll
        for (int nt = 0; nt < 4; ++nt) {
            const int col = n0 + nt * 16 + l16;
#pragma unroll
            for (int mt = 0; mt < 2; ++mt)
#pragma unroll
                for (int reg = 0; reg < 4; ++reg) {
                    const size_t m = (size_t)(m0 + w * 32 + mt * 16 + quad * 4 + reg);
                    krel[m * 512 + col] = (ushort_t)bf16r(acc[mt][nt][reg]);
                }
        }
    }
}

// ---------------------------------------------------------------------------
// Kernel 3: rel GEMM, now writing R in ATTENTION'S CONSUMPTION LAYOUT:
// R3[(b*8+n)*2048 + i][cslot] with cslot = (i&31) + 256 - r  (in [0,288)).
// attn's (32-q tile, chunk c) R block is then the contiguous panel
// rows i0..i0+31, cols c*64..c*64+63 -> coalesced b128 staging instead of
// 80 scattered 2-byte gathers per thread (R was ~30 of attn's 47 MB FETCH).
// Grid (17,8,2): tile<16 = GEMM; tile==16 = vmean fold.
// ---------------------------------------------------------------------------
__global__ __launch_bounds__(256) void rel_gemm(
    const ushort_t* __restrict__ qrel, const ushort_t* __restrict__ krel,
    const ushort_t* __restrict__ vT, ushort_t* __restrict__ R3,
    float* __restrict__ vmean)
{
    const int tile = blockIdx.x, n = blockIdx.y, b = blockIdx.z;
    const int tid = threadIdx.x, lane = tid & 63, w = tid >> 6;
    const int quad = lane >> 4, l16 = lane & 15;

    __shared__ __align__(16) ushort_t A_lds[128][LP];
    __shared__ __align__(16) ushort_t B_lds[64][LP];

    if (tile == 16) {
        // ---- vmean: rows (b*8+n)*64 + d of vT, mean over 2048 ----
        const int row = tid >> 2, seg = tid & 3;
        const ushort_t* src = &vT[((size_t)((b * NH + n) * 64 + row)) * 2048 + seg * 512];
        float sum = 0.f;
        for (int it = 0; it < 64; ++it) {
            short8 h = *(const short8*)(src + it * 8);
#pragma unroll
            for (int u = 0; u < 8; ++u) sum += b2f((ushort_t)h[u]);
        }
        float* scratch = (float*)A_lds;
        scratch[row * 4 + seg] = sum;
        __syncthreads();
        if (tid < 64) {
            float s = scratch[tid * 4] + scratch[tid * 4 + 1]
                    + scratch[tid * 4 + 2] + scratch[tid * 4 + 3];
            vmean[(size_t)b * 512 + n * 64 + tid] = s * (1.0f / (float)S_);
        }
        return;
    }

    const int i0 = tile * 128;
    {
        const int srow = tid >> 1, sc0 = (tid & 1) * 32;
        const ushort_t* src = &qrel[((size_t)b * S_ + i0 + srow) * 512 + n * 64 + sc0];
#pragma unroll
        for (int u = 0; u < 4; ++u)
            *(short8*)&A_lds[srow][sc0 + u * 8] = *(const short8*)(src + u * 8);
    }

    const size_t rbase3 = (size_t)(b * NH + n) * S_ * CSL;
    const int srow2 = tid >> 2, sc2 = (tid & 3) * 16;

    short8 pb0, pb1;
    auto issueB = [&](int rc) {
        const ushort_t* src = &krel[(size_t)(rc * 64 + srow2) * 512 + n * 64 + sc2];
        pb0 = *(const short8*)src;
        pb1 = *(const short8*)(src + 8);
    };
    issueB(0);

#pragma unroll 1
    for (int rc = 0; rc < 5; ++rc) {
        __syncthreads();   // A visible (rc==0) / prev chunk's B reads done
        *(short8*)&B_lds[srow2][sc2]     = pb0;
        *(short8*)&B_lds[srow2][sc2 + 8] = pb1;
        if (rc < 4) issueB(rc + 1);
        __syncthreads();

        short8 a[2][2];
#pragma unroll
        for (int mt = 0; mt < 2; ++mt) {
            a[mt][0] = *(const short8*)&A_lds[w * 32 + mt * 16 + l16][quad * 8];
            a[mt][1] = *(const short8*)&A_lds[w * 32 + mt * 16 + l16][quad * 8 + 32];
        }
#pragma unroll
        for (int nt = 0; nt < 4; ++nt) {
            short8 b0 = *(const short8*)&B_lds[nt * 16 + l16][quad * 8];
            short8 b1 = *(const short8*)&B_lds[nt * 16 + l16][quad * 8 + 32];
            const int r = rc * 64 + nt * 16 + l16;
#pragma unroll
            for (int mt = 0; mt < 2; ++mt) {
                f32x4 s = (f32x4){0.f, 0.f, 0.f, 0.f};
                s = __builtin_amdgcn_mfma_f32_16x16x32_bf16(a[mt][0], b0, s, 0, 0, 0);
                s = __builtin_amdgcn_mfma_f32_16x16x32_bf16(a[mt][1], b1, s, 0, 0, 0);
                if (r <= 256) {
#pragma unroll
                    for (int reg = 0; reg < 4; ++reg) {
                        const int ig = i0 + w * 32 + mt * 16 + quad * 4 + reg;
                        const int cslot = (ig & 31) + 256 - r;
                        R3[rbase3 + (size_t)ig * CSL + cslot] = (ushort_t)bf16r(s[reg]);
                    }
                }
            }
        }
    }
}

// ---------------------------------------------------------------------------
// Kernel 5: banded attention via bf16 MFMA.  R13 structure + R3 layout:
// R staged per chunk as a contiguous 32x64 bf16 panel (coalesced short8
// prefetch -> Rl_lds), replacing the per-slot global gather.  LDS 32.2 KB
// -> 4 blocks/CU (grid 1024 = 4/CU).
// ---------------------------------------------------------------------------
__global__ __launch_bounds__(128) void attn_kernel(
    const ushort_t* __restrict__ qcon, const ushort_t* __restrict__ kbuf,
    const ushort_t* __restrict__ vT, const ushort_t* __restrict__ R3,
    const float* __restrict__ vmean, const int* __restrict__ xlen_p,
    float* __restrict__ out)
{
    const int bx = blockIdx.x;
    const int tile = ((bx & 7) << 3) | (bx >> 3);   // XCD swizzle
    const int n = blockIdx.y, b = blockIdx.z;
    const int i0 = tile * 32;
    const int tid = threadIdx.x, lane = tid & 63, w = tid >> 6;
    const int quad = lane >> 4, l16 = lane & 15;
    const int xlen = xlen_p[b];

    __shared__ __align__(16) ushort_t q_lds[32][LP];
    __shared__ __align__(16) ushort_t k_lds[64][LP];
    __shared__ __align__(16) ushort_t vT_lds[64][LP];
    __shared__ __align__(16) ushort_t p_lds[32][LP];
    __shared__ __align__(16) ushort_t Rl_lds[32][LP];

    {
        const int qr = tid >> 2, qc = (tid & 3) * 16;
        const ushort_t* src = &qcon[((size_t)b * S_ + i0 + qr) * 512 + n * 64 + qc];
        *(short8*)&q_lds[qr][qc]     = *(const short8*)src;
        *(short8*)&q_lds[qr][qc + 8] = *(const short8*)(src + 8);
    }

    f32x4 Oa[4];
#pragma unroll
    for (int nt = 0; nt < 4; ++nt) Oa[nt] = (f32x4){0.f, 0.f, 0.f, 0.f};
    float lpart[4] = {};

    const size_t rbase3 = (size_t)(b * NH + n) * S_ * CSL;
    const size_t vTbase = (size_t)((b * NH + n) * 64) * 2048;
    const int srow = tid >> 1, sc0 = (tid & 1) * 32;      // k/vT staging
    const int rrow = tid >> 2, rcol = (tid & 3) * 16;     // R panel staging
    const short8 z8 = {0, 0, 0, 0, 0, 0, 0, 0};

    short8 kr[4], vr[4], kn[4], vn[4];
    short8 rcur[2], rnxt[2];

    auto issue = [&](int c, short8* kd, short8* vd, short8* rd) {
        const int jc0 = i0 - 256 + c * 64;
        const int jg = jc0 + srow;
        const bool okk = (jg >= 0);
        const ushort_t* ks = &kbuf[((size_t)b * S_ + jg) * 512 + n * 64 + sc0];
        const ushort_t* vs = &vT[vTbase + (size_t)srow * 2048 + jc0 + sc0];
#pragma unroll
        for (int u = 0; u < 4; ++u) {
            kd[u] = okk ? *(const short8*)(ks + u * 8) : z8;
            const bool okv = (jc0 + sc0 + u * 8) >= 0;
            vd[u] = okv ? *(const short8*)(vs + u * 8) : z8;
        }
        // R panel: rows i0..i0+31, cols c*64 + rcol .. +15 (contiguous)
        const ushort_t* Rs = &R3[rbase3 + (size_t)(i0 + rrow) * CSL + c * 64 + rcol];
        rd[0] = *(const short8*)Rs;
        rd[1] = *(const short8*)(Rs + 8);
    };

    issue(0, kr, vr, rcur);

#pragma unroll 1
    for (int c = 0; c < 5; ++c) {
        const int jc0 = i0 - 256 + c * 64;
        __syncthreads();   // prev-chunk PV reads of k/vT/p + exp reads of Rl done
#pragma unroll
        for (int u = 0; u < 4; ++u) {
            *(short8*)&k_lds[srow][sc0 + u * 8]  = kr[u];
            *(short8*)&vT_lds[srow][sc0 + u * 8] = vr[u];
        }
        *(short8*)&Rl_lds[rrow][rcol]     = rcur[0];
        *(short8*)&Rl_lds[rrow][rcol + 8] = rcur[1];
        if (c < 4) issue(c + 1, kn, vn, rnxt);
        __syncthreads();

        // ---- QK ----
        short8 aq0 = *(const short8*)&q_lds[w * 16 + l16][quad * 8];
        short8 aq1 = *(const short8*)&q_lds[w * 16 + l16][quad * 8 + 32];
        f32x4 Sacc[4];
#pragma unroll
        for (int jt = 0; jt < 4; ++jt) {
            short8 bk0 = *(const short8*)&k_lds[jt * 16 + l16][quad * 8];
            short8 bk1 = *(const short8*)&k_lds[jt * 16 + l16][quad * 8 + 32];
            f32x4 s = (f32x4){0.f, 0.f, 0.f, 0.f};
            s = __builtin_amdgcn_mfma_f32_16x16x32_bf16(aq0, bk0, s, 0, 0, 0);
            s = __builtin_amdgcn_mfma_f32_16x16x32_bf16(aq1, bk1, s, 0, 0, 0);
            Sacc[jt] = s;
        }

        // ---- mask + rel bias (Rl_lds[row][jcol]) + exp; p -> LDS bf16 ----
#pragma unroll
        for (int jt = 0; jt < 4; ++jt) {
#pragma unroll
            for (int reg = 0; reg < 4; ++reg) {
                const int row = w * 16 + quad * 4 + reg;
                const int i = i0 + row;
                const int j = jc0 + jt * 16 + l16;
                const int r = i - j;
                const bool valid = (j >= 0) && (j < xlen) && (r >= 0) && (r <= 256);
                float rvv = b2f(Rl_lds[row][jt * 16 + l16]);
                float e = valid ? __expf(Sacc[jt][reg] + rvv) : 0.f;
                lpart[reg] += e;
                p_lds[row][jt * 16 + l16] = (ushort_t)bf16r(e);
            }
        }
        __syncthreads();

        // ---- PV ----
        short8 ap0 = *(const short8*)&p_lds[w * 16 + l16][quad * 8];
        short8 ap1 = *(const short8*)&p_lds[w * 16 + l16][quad * 8 + 32];
#pragma unroll
        for (int nt = 0; nt < 4; ++nt) {
            short8 bv0 = *(const short8*)&vT_lds[nt * 16 + l16][quad * 8];
            short8 bv1 = *(const short8*)&vT_lds[nt * 16 + l16][quad * 8 + 32];
            Oa[nt] = __builtin_amdgcn_mfma_f32_16x16x32_bf16(ap0, bv0, Oa[nt], 0, 0, 0);
            Oa[nt] = __builtin_amdgcn_mfma_f32_16x16x32_bf16(ap1, bv1, Oa[nt], 0, 0, 0);
        }

        // ---- rotate register sets ----
#pragma unroll
        for (int u = 0; u < 4; ++u) { kr[u] = kn[u]; vr[u] = vn[u]; }
        rcur[0] = rnxt[0]; rcur[1] = rnxt[1];
    }

#pragma unroll
    for (int reg = 0; reg < 4; ++reg) {
#pragma unroll
        for (int off = 1; off < 16; off <<= 1)
            lpart[reg] += __shfl_xor(lpart[reg], off, 64);
    }

#pragma unroll
    for (int reg = 0; reg < 4; ++reg) {
        const int i = i0 + w * 16 + quad * 4 + reg;
        const bool dead = (i >= xlen + 256);
        const float linv = 1.0f / lpart[reg];
#pragma unroll
        for (int nt = 0; nt < 4; ++nt) {
            const int d = n * 64 + nt * 16 + l16;
            float val = dead ? vmean[(size_t)b * 512 + d] : Oa[nt][reg] * linv;
            out[((size_t)b * S_ + i) * 512 + d] = val;
        }
    }
}

// ---------------------------------------------------------------------------
extern "C" void kernel_launch(void* const* d_in, const int* in_sizes, int n_in,
                              void* d_out, int out_size, void* d_ws, size_t ws_size,
                              hipStream_t stream) {
    const float* x     = (const float*)d_in[0];
    const float* Wq    = (const float*)d_in[1];
    const float* b_con = (const float*)d_in[2];
    const float* b_rel = (const float*)d_in[3];
    const float* Wk    = (const float*)d_in[4];
    const float* Wkr   = (const float*)d_in[5];
    const float* Wv    = (const float*)d_in[6];
    const float* bv    = (const float*)d_in[7];
    const int*   xlen  = (const int*)d_in[8];
    float* out = (float*)d_out;

    float* ws = (float*)d_ws;
    float* vmean = ws;                       // 1024 fp32
    ushort_t* ub   = (ushort_t*)(vmean + 1024);
    ushort_t* R3   = ub;                     // 16*2048*320 bf16 = 21 MB
    ushort_t* qcon = R3   + 10485760;
    ushort_t* kbuf = qcon + 2097152;
    ushort_t* vT   = kbuf + 2097152;         // 1024 x 2048 bf16
    ushort_t* qrel = vT   + 2097152;
    ushort_t* xb16 = qrel + 2097152;         // 4096*512 bf16
    ushort_t* krel = xb16 + 2097152;         // 384*512 bf16
    ushort_t* pos  = krel + 196608;          // 384*512 bf16
    ushort_t* WTq  = pos  + 196608;          // 512*512 bf16 each
    ushort_t* WTk  = WTq + 262144;
    ushort_t* WTv  = WTk + 262144;
    ushort_t* WTkr = WTv + 262144;

    prep_kernel<<<dim3(8, 8, 6), 256, 0, stream>>>(x, Wq, Wk, Wv, Wkr,
                                                   WTq, WTk, WTv, WTkr, pos, xb16);
    qkv_gemm<<<dim3(32, 25), 256, 0, stream>>>(xb16, WTq, WTk, WTv, pos, WTkr,
                                               b_con, b_rel, bv,
                                               qcon, qrel, kbuf, vT, krel);
    rel_gemm<<<dim3(17, 8, 2), 256, 0, stream>>>(qrel, krel, vT, R3, vmean);
    attn_kernel<<<dim3(64, 8, 2), 128, 0, stream>>>(qcon, kbuf, vT, R3, vmean,
                                                    xlen, out);
}